// Round 6
// baseline (151.986 us; speedup 1.0000x reference)
//
#include <hip/hip_runtime.h>
#include <hip/hip_bf16.h>
#include <math.h>

#define NN 4096
#define DD 256
#define TWO_N 8192
#define SCALE 14.426950408889634f   // (1/T)*log2(e)
#define INV_2N (1.0f/8192.0f)

typedef __bf16 bf16_t;
typedef bf16_t bf16x8 __attribute__((ext_vector_type(8)));
typedef bf16_t bf16x4 __attribute__((ext_vector_type(4)));
typedef float f32x4 __attribute__((ext_vector_type(4)));

// ---------------- normalize rows -> bf16 Zn ; zero possum/out ----------------
__global__ __launch_bounds__(256) void knorm(const float* __restrict__ zi,
                                             const float* __restrict__ zj,
                                             bf16_t* __restrict__ zn,
                                             float* __restrict__ possum,
                                             float* __restrict__ out) {
    const int wid = threadIdx.x >> 6, lane = threadIdx.x & 63;
    const int b = blockIdx.x;
    if (b == 0 && threadIdx.x == 0) { possum[0] = 0.0f; out[0] = 0.0f; }
    const int row = b * 4 + wid;                   // grid = 2048 -> rows 0..8191
    const float* src = (row < NN) ? (zi + (size_t)row * DD)
                                  : (zj + (size_t)(row - NN) * DD);
    float4 v = *(const float4*)(src + lane * 4);
    float ss = v.x*v.x + v.y*v.y + v.z*v.z + v.w*v.w;
    #pragma unroll
    for (int m = 1; m < 64; m <<= 1) ss += __shfl_xor(ss, m);
    const float sc = 1.0f / fmaxf(sqrtf(ss), 1e-8f);
    bf16x4 o;
    o[0] = (bf16_t)(v.x * sc);
    o[1] = (bf16_t)(v.y * sc);
    o[2] = (bf16_t)(v.z * sc);
    o[3] = (bf16_t)(v.w * sc);
    *(bf16x4*)(zn + (size_t)row * DD + lane * 4) = o;
}

// ---------------- main: upper-triangular 128x128 tiles of exp(sim/T) ----------------
// grid = 2080 (= 64*65/2) blocks, 256 threads (4 waves in 2x2), NO LDS, NO barriers.
// All fragments loaded straight from L2-resident zn (4 MB), ping-pong double-buffered
// in registers. 8 K-steps of 32; 16 MFMA per step per wave.
__global__ __launch_bounds__(256, 3) void kmain(const bf16_t* __restrict__ zn,
                                                float* __restrict__ PR,
                                                float* __restrict__ PC,
                                                float* __restrict__ possum) {
    const int tid = threadIdx.x, wid = tid >> 6, lane = tid & 63;

    // triangular decode (uniform scalar loop)
    int ti = 0, rem = (int)blockIdx.x;
    while (rem >= 64 - ti) { rem -= 64 - ti; ++ti; }
    const int tj = ti + rem;
    const int rowbase = ti << 7, colbase = tj << 7;

    const int wr = wid >> 1, wc = wid & 1;         // 2x2 wave grid, 64x64 each
    const int lo = lane & 15, hi = lane >> 4;

    // per-lane base pointers: A rows (rowbase + wr*64 + s*16 + lo),
    // B rows (colbase + wc*64 + t*16 + lo); k-offset = ks*32 + hi*8 elements.
    const bf16_t* pa = zn + (size_t)(rowbase + wr * 64 + lo) * DD + hi * 8;
    const bf16_t* pb = zn + (size_t)(colbase + wc * 64 + lo) * DD + hi * 8;

    f32x4 acc[4][4];
    #pragma unroll
    for (int s = 0; s < 4; ++s)
        #pragma unroll
        for (int t = 0; t < 4; ++t) acc[s][t] = (f32x4){0, 0, 0, 0};

    bf16x8 a0[4], b0[4], a1[4], b1[4];

    #pragma unroll
    for (int s = 0; s < 4; ++s) {
        a0[s] = *(const bf16x8*)(pa + (size_t)s * 16 * DD);
        b0[s] = *(const bf16x8*)(pb + (size_t)s * 16 * DD);
    }

    #pragma unroll
    for (int ks = 0; ks < 8; ++ks) {
        const int kofs = (ks + 1) * 32;
        if ((ks & 1) == 0) {
            if (ks < 7) {
                #pragma unroll
                for (int s = 0; s < 4; ++s) {
                    a1[s] = *(const bf16x8*)(pa + (size_t)s * 16 * DD + kofs);
                    b1[s] = *(const bf16x8*)(pb + (size_t)s * 16 * DD + kofs);
                }
            }
            #pragma unroll
            for (int s = 0; s < 4; ++s)
                #pragma unroll
                for (int t = 0; t < 4; ++t)
                    acc[s][t] = __builtin_amdgcn_mfma_f32_16x16x32_bf16(
                        a0[s], b0[t], acc[s][t], 0, 0, 0);
        } else {
            if (ks < 7) {
                #pragma unroll
                for (int s = 0; s < 4; ++s) {
                    a0[s] = *(const bf16x8*)(pa + (size_t)s * 16 * DD + kofs);
                    b0[s] = *(const bf16x8*)(pb + (size_t)s * 16 * DD + kofs);
                }
            }
            #pragma unroll
            for (int s = 0; s < 4; ++s)
                #pragma unroll
                for (int t = 0; t < 4; ++t)
                    acc[s][t] = __builtin_amdgcn_mfma_f32_16x16x32_bf16(
                        a1[s], b1[t], acc[s][t], 0, 0, 0);
        }
    }

    // ---- positives: diagonal of tiles with tj == ti+32 (col = row + 4096) ----
    if (tj == ti + 32 && wr == wc) {
        const int j = lo - hi * 4;                 // C layout: col=lo, row=hi*4+j
        float p = 0.0f;
        if (j >= 0 && j < 4) {
            #pragma unroll
            for (int s = 0; s < 4; ++s) p += acc[s][s][j];
        }
        #pragma unroll
        for (int m = 1; m < 64; m <<= 1) p += __shfl_xor(p, m);
        if (lane == 0) atomicAdd(possum, p);
    }

    // ---- snap self-similarity diagonal to exactly 1.0 (kills bf16 diag error) ----
    if (ti == tj && wr == wc) {
        const int j = lo - hi * 4;
        if (j >= 0 && j < 4) {
            #pragma unroll
            for (int s = 0; s < 4; ++s) acc[s][s][j] = 1.0f;
        }
    }

    // ---- exp in place ----
    #pragma unroll
    for (int s = 0; s < 4; ++s)
        #pragma unroll
        for (int t = 0; t < 4; ++t)
            #pragma unroll
            for (int j = 0; j < 4; ++j)
                acc[s][t][j] = __builtin_amdgcn_exp2f(acc[s][t][j] * SCALE);

    // ---- row partial sums -> PR[ti][tj][wc][wr*64 + r]  (plain stores) ----
    {
        float* PRb = PR + (((size_t)(ti * 64 + tj) * 2 + wc) << 7) + wr * 64;
        #pragma unroll
        for (int s = 0; s < 4; ++s) {
            f32x4 rs = acc[s][0] + acc[s][1] + acc[s][2] + acc[s][3];
            #pragma unroll
            for (int j = 0; j < 4; ++j) {
                float v = rs[j];
                v += __shfl_xor(v, 1); v += __shfl_xor(v, 2);
                v += __shfl_xor(v, 4); v += __shfl_xor(v, 8);
                if (lo == 0) PRb[s * 16 + hi * 4 + j] = v;
            }
        }
    }

    // ---- col partial sums -> PC[tj][ti][wr][wc*64 + c]  (off-diagonal only) ----
    if (ti != tj) {
        float* PCb = PC + (((size_t)(tj * 64 + ti) * 2 + wr) << 7) + wc * 64;
        #pragma unroll
        for (int t = 0; t < 4; ++t) {
            float v = 0.0f;
            #pragma unroll
            for (int s = 0; s < 4; ++s)
                v += acc[s][t][0] + acc[s][t][1] + acc[s][t][2] + acc[s][t][3];
            v += __shfl_xor(v, 16); v += __shfl_xor(v, 32);
            if (hi == 0) PCb[t * 16 + lo] = v;
        }
    }
}

// ---------------- final: gather partials, logs, scalar reduction ----------------
// grid = 64 blocks (one per tile-row a) x 128 threads (one per row in tile).
// Reads ONLY written slots: PR[a][t>=a][*][rr], PC[a][b<a][*][rr] -> 128 loads/thread.
__global__ __launch_bounds__(128) void kfinal(const float* __restrict__ PR,
                                              const float* __restrict__ PC,
                                              const float* __restrict__ possum,
                                              float* __restrict__ out) {
    __shared__ float red[2];
    const int a = blockIdx.x;
    const int rr = threadIdx.x;                    // 0..127
    const int wid = threadIdx.x >> 6, lane = threadIdx.x & 63;
    float total = 0.0f;
    for (int t = a; t < 64; ++t) {
        total += PR[(((size_t)(a * 64 + t) * 2 + 0) << 7) + rr];
        total += PR[(((size_t)(a * 64 + t) * 2 + 1) << 7) + rr];
    }
    for (int b = 0; b < a; ++b) {
        total += PC[(((size_t)(a * 64 + b) * 2 + 0) << 7) + rr];
        total += PC[(((size_t)(a * 64 + b) * 2 + 1) << 7) + rr];
    }
    float v = logf(total * INV_2N);
    #pragma unroll
    for (int m = 1; m < 64; m <<= 1) v += __shfl_xor(v, m);
    if (lane == 0) red[wid] = v;
    __syncthreads();
    if (threadIdx.x == 0) {
        float s = red[0] + red[1];
        if (a == 0) s -= 20.0f * possum[0];        // (1/T)*sum(pos), pos counted twice
        atomicAdd(out, s * INV_2N);
    }
}

extern "C" void kernel_launch(void* const* d_in, const int* in_sizes, int n_in,
                              void* d_out, int out_size, void* d_ws, size_t ws_size,
                              hipStream_t stream) {
    const float* zi = (const float*)d_in[0];
    const float* zj = (const float*)d_in[1];
    bf16_t* zn     = (bf16_t*)d_ws;                                  // [0, 4MB)
    float*  PR     = (float*)((char*)d_ws + ((size_t)4 << 20));      // [4MB, 8MB)
    float*  PC     = (float*)((char*)d_ws + ((size_t)8 << 20));      // [8MB, 12MB)
    float*  possum = (float*)((char*)d_ws + ((size_t)12 << 20));
    float*  out    = (float*)d_out;

    knorm <<<2048, 256, 0, stream>>>(zi, zj, zn, possum, out);
    kmain <<<2080, 256, 0, stream>>>(zn, PR, PC, possum);
    kfinal<<<64,   128, 0, stream>>>(PR, PC, possum, out);
}